// Round 1
// baseline (17684.270 us; speedup 1.0000x reference)
//
#include <hip/hip_runtime.h>

#define NN 512
#define BB 64
#define TT 1000

// ---------------------------------------------------------------------------
// Transpose W[n][k] -> Wt[k][n] so the matvec reads are lane-coalesced.
// Standard 32x32 LDS tile, 256 threads (32x8).
// ---------------------------------------------------------------------------
__global__ __launch_bounds__(256) void transpose_w(const float* __restrict__ W,
                                                   float* __restrict__ Wt) {
    __shared__ float tile[32][33];
    const int tx = threadIdx.x & 31;
    const int ty = threadIdx.x >> 5;          // 0..7
    const int n0 = blockIdx.x * 32;
    const int k0 = blockIdx.y * 32;
#pragma unroll
    for (int i = 0; i < 32; i += 8)
        tile[ty + i][tx] = W[(size_t)(n0 + ty + i) * NN + (k0 + tx)];
    __syncthreads();
#pragma unroll
    for (int i = 0; i < 32; i += 8)
        Wt[(size_t)(k0 + ty + i) * NN + (n0 + tx)] = tile[tx][ty + i];
}

// ---------------------------------------------------------------------------
// Persistent scan: one workgroup per batch element (64 WGs), T-loop inside.
// No cross-workgroup dependency (batches independent, W shared read-only).
// Thread tid owns hidden elements n = {2*tid, 2*tid+1} (float2).
// Per step: th = tanh(h) -> LDS; h_new[n] = 0.9 h + 0.1(sum_k th[k]*Wt[k][n] + x).
// ---------------------------------------------------------------------------
__global__ __launch_bounds__(256) void rnn_scan(const float* __restrict__ h0v,
                                                const float* __restrict__ X,
                                                const float* __restrict__ Wt,
                                                float* __restrict__ hid) {
    const int b = blockIdx.x;
    const int tid = threadIdx.x;
    __shared__ float th[NN];

    float2 h = *reinterpret_cast<const float2*>(h0v + 2 * tid);
    const float* xb = X + (size_t)b * TT * NN;

    for (int t = 0; t < TT; ++t) {
        th[2 * tid]     = tanhf(h.x);
        th[2 * tid + 1] = tanhf(h.y);
        __syncthreads();

        float a0 = 0.f, a1 = 0.f;
        const float2* w = reinterpret_cast<const float2*>(Wt) + tid;  // Wt[k][2*tid]
#pragma unroll 4
        for (int k = 0; k < NN; ++k) {
            const float s = th[k];
            const float2 wv = w[(size_t)k * (NN / 2)];
            a0 = fmaf(s, wv.x, a0);
            a1 = fmaf(s, wv.y, a1);
        }

        const float2 x = *reinterpret_cast<const float2*>(xb + (size_t)t * NN + 2 * tid);
        h.x = 0.9f * h.x + 0.1f * (a0 + x.x);
        h.y = 0.9f * h.y + 0.1f * (a1 + x.y);

        *reinterpret_cast<float2*>(hid + ((size_t)t * BB + b) * NN + 2 * tid) = h;
        __syncthreads();   // before next step's th writes
    }
}

// ---------------------------------------------------------------------------
// geometry = tanh(hidden_t) @ G_w.T + G_b ; readout = geometry @ D.T
// One wave per (t,b) row: 8 elements/lane, shuffle reduce, lane 0 writes.
// ---------------------------------------------------------------------------
__global__ __launch_bounds__(256) void geo_read(const float* __restrict__ hid,
                                                const float* __restrict__ Gw,
                                                const float* __restrict__ Gb,
                                                float* __restrict__ geo,
                                                float* __restrict__ rdo) {
    const int wave = (int)((blockIdx.x * 256 + threadIdx.x) >> 6);  // 0..63999
    const int lane = threadIdx.x & 63;
    if (wave >= TT * BB) return;

    const float* hrow = hid + (size_t)wave * NN;
    float g0 = 0.f, g1 = 0.f;
#pragma unroll
    for (int i = 0; i < 2; ++i) {             // 2 x float4 per lane = 8 elems
        const int off = i * 256 + lane * 4;
        const float4 hv  = *reinterpret_cast<const float4*>(hrow + off);
        const float4 w0  = *reinterpret_cast<const float4*>(Gw + off);
        const float4 w1  = *reinterpret_cast<const float4*>(Gw + NN + off);
        const float t0 = tanhf(hv.x), t1 = tanhf(hv.y), t2 = tanhf(hv.z), t3 = tanhf(hv.w);
        g0 = fmaf(t0, w0.x, fmaf(t1, w0.y, fmaf(t2, w0.z, fmaf(t3, w0.w, g0))));
        g1 = fmaf(t0, w1.x, fmaf(t1, w1.y, fmaf(t2, w1.z, fmaf(t3, w1.w, g1))));
    }
#pragma unroll
    for (int off = 32; off > 0; off >>= 1) {
        g0 += __shfl_down(g0, off);
        g1 += __shfl_down(g1, off);
    }
    if (lane == 0) {
        g0 += Gb[0];
        g1 += Gb[1];
        geo[(size_t)wave * 2 + 0] = g0;
        geo[(size_t)wave * 2 + 1] = g1;
        // Fixed readout directions: D[k] = (cos(k*pi/3), sin(k*pi/3))
        const float dc[6] = {1.0f, 0.5f, -0.5f, -1.0f, -0.5f, 0.5f};
        const float ds[6] = {0.0f, 0.86602540378443865f, 0.86602540378443871f,
                             1.2246467991473532e-16f, -0.86602540378443837f,
                             -0.86602540378443860f};
#pragma unroll
        for (int k = 0; k < 6; ++k)
            rdo[(size_t)wave * 6 + k] = fmaf(g0, dc[k], g1 * ds[k]);
    }
}

extern "C" void kernel_launch(void* const* d_in, const int* in_sizes, int n_in,
                              void* d_out, int out_size, void* d_ws, size_t ws_size,
                              hipStream_t stream) {
    const float* h0 = (const float*)d_in[0];   // [512]
    const float* X  = (const float*)d_in[1];   // [64,1000,512]
    const float* W  = (const float*)d_in[2];   // [512,512]
    const float* Gw = (const float*)d_in[3];   // [2,512]
    const float* Gb = (const float*)d_in[4];   // [2]

    float* out = (float*)d_out;
    float* hid = out;                                   // [T*B*N]
    float* geo = out + (size_t)TT * BB * NN;            // [T*B*2]
    float* rdo = geo + (size_t)TT * BB * 2;             // [T*B*6]

    // Scratch for Wt (1 MB fp32). Fall back to the geo+readout region
    // (2 MB, written only by the later geo_read pass) if ws is too small.
    float* Wt = (ws_size >= (size_t)NN * NN * sizeof(float)) ? (float*)d_ws : geo;

    transpose_w<<<dim3(16, 16), 256, 0, stream>>>(W, Wt);
    rnn_scan<<<BB, 256, 0, stream>>>(h0, X, Wt, hid);
    geo_read<<<(TT * BB) / 4, 256, 0, stream>>>(hid, Gw, Gb, geo, rdo);
}

// Round 2
// 7692.400 us; speedup vs baseline: 2.2989x; 2.2989x over previous
//
#include <hip/hip_runtime.h>

#define NN 512
#define BB 64
#define TT 1000

typedef unsigned int u32;
typedef _Float16 h2_t __attribute__((ext_vector_type(2)));

// ---------------------------------------------------------------------------
// v_dot2_f32_f16: acc += s[0]*w[0] + s[1]*w[1]  (f16 inputs, f32 accumulate)
// ---------------------------------------------------------------------------
__device__ inline float fdot2u(u32 su, u32 wu, float acc) {
#if __has_builtin(__builtin_amdgcn_fdot2)
    return __builtin_amdgcn_fdot2(__builtin_bit_cast(h2_t, su),
                                  __builtin_bit_cast(h2_t, wu), acc, false);
#else
    h2_t s = __builtin_bit_cast(h2_t, su);
    h2_t w = __builtin_bit_cast(h2_t, wu);
    return fmaf((float)s[0], (float)w[0], fmaf((float)s[1], (float)w[1], acc));
#endif
}

// ---------------------------------------------------------------------------
// Pack W[n][k] (f32) -> Wp[kp][n] (u32 = half2(W[n][2kp], W[n][2kp+1])).
// k-pairs adjacent in one dword so v_dot2 consumes them directly; n is the
// fast axis so the scan's loads are lane-coalesced.
// ---------------------------------------------------------------------------
__global__ __launch_bounds__(256) void pack_w(const float* __restrict__ W,
                                              u32* __restrict__ Wp) {
    const int n = blockIdx.x;      // 0..511
    const int j = threadIdx.x;     // kp 0..255
    const float2 w = reinterpret_cast<const float2*>(W + (size_t)n * NN)[j];
    h2_t h;
    h[0] = (_Float16)w.x;
    h[1] = (_Float16)w.y;
    Wp[(size_t)j * NN + n] = __builtin_bit_cast(u32, h);
}

// ---------------------------------------------------------------------------
// Persistent scan: one WG per batch (64 WGs), 1024 threads = 16 waves
// (4/SIMD for latency hiding). Thread (ks = tid>>8, c = tid&255) computes
// partial sums over k in [ks*128, ks*128+128) for columns {2c, 2c+1}.
// Threads tid<512 own hidden element n=tid (state h, x prefetch, reduce).
// Per step: tanh->LDS | barrier | dot2 matvec partials + x prefetch |
// barrier | 4-way reduce + state update + store.
// ---------------------------------------------------------------------------
__global__ __launch_bounds__(1024) void rnn_scan(const float* __restrict__ h0v,
                                                 const float* __restrict__ X,
                                                 const u32* __restrict__ Wp,
                                                 float* __restrict__ hid) {
    const int b = blockIdx.x;
    const int tid = threadIdx.x;
    const int c = tid & 255;
    const int ks = tid >> 8;

    __shared__ __attribute__((aligned(16))) unsigned short th_h[NN];  // tanh(h) as f16
    __shared__ float2 part[4][256];                                   // k-split partials

    const float* xb = X + (size_t)b * TT * NN;
    float h = 0.f, xn = 0.f;
    if (tid < NN) {
        h = h0v[tid];
        xn = xb[tid];
    }

    // Per-thread W base: k-pair window starts at kp = ks*64; cols {2c,2c+1}.
    const uint2* wp = reinterpret_cast<const uint2*>(Wp) + (size_t)(ks * 64) * 256 + c;
    const uint4* thv = reinterpret_cast<const uint4*>(th_h) + ks * 16;
    const float* pf = reinterpret_cast<const float*>(part);  // flat: pf[ks*512 + n]

    for (int t = 0; t < TT; ++t) {
        if (tid < NN) {
            const _Float16 hh = (_Float16)tanhf(h);
            th_h[tid] = __builtin_bit_cast(unsigned short, hh);
        }
        __syncthreads();

        // Prefetch next x (HBM latency hides under the matvec).
        float xnext = 0.f;
        if (tid < NN && t + 1 < TT) xnext = xb[(size_t)(t + 1) * NN + tid];

        float a0 = 0.f, a1 = 0.f;
#pragma unroll 4
        for (int q = 0; q < 16; ++q) {       // 4 k-pairs (8 k) per iteration
            const uint4 s = thv[q];          // ds_read_b128: 8 tanh values
            const uint2 w0 = wp[(q * 4 + 0) * 256];
            const uint2 w1 = wp[(q * 4 + 1) * 256];
            const uint2 w2 = wp[(q * 4 + 2) * 256];
            const uint2 w3 = wp[(q * 4 + 3) * 256];
            a0 = fdot2u(s.x, w0.x, a0);
            a1 = fdot2u(s.x, w0.y, a1);
            a0 = fdot2u(s.y, w1.x, a0);
            a1 = fdot2u(s.y, w1.y, a1);
            a0 = fdot2u(s.z, w2.x, a0);
            a1 = fdot2u(s.z, w2.y, a1);
            a0 = fdot2u(s.w, w3.x, a0);
            a1 = fdot2u(s.w, w3.y, a1);
        }
        part[ks][c] = make_float2(a0, a1);
        __syncthreads();

        if (tid < NN) {
            const float s = (pf[tid] + pf[512 + tid]) + (pf[1024 + tid] + pf[1536 + tid]);
            h = 0.9f * h + 0.1f * (s + xn);
            hid[((size_t)t * BB + b) * NN + tid] = h;
            xn = xnext;
        }
        // No barrier needed here: next phase-A writes th_h (not part), and the
        // next phase-B (which rewrites part) is behind the phase-A barrier.
    }
}

// ---------------------------------------------------------------------------
// geometry = tanh(hidden_t) @ G_w.T + G_b ; readout = geometry @ D.T
// One wave per (t,b) row: 8 elements/lane, shuffle reduce, lane 0 writes.
// ---------------------------------------------------------------------------
__global__ __launch_bounds__(256) void geo_read(const float* __restrict__ hid,
                                                const float* __restrict__ Gw,
                                                const float* __restrict__ Gb,
                                                float* __restrict__ geo,
                                                float* __restrict__ rdo) {
    const int wave = (int)((blockIdx.x * 256 + threadIdx.x) >> 6);  // 0..63999
    const int lane = threadIdx.x & 63;
    if (wave >= TT * BB) return;

    const float* hrow = hid + (size_t)wave * NN;
    float g0 = 0.f, g1 = 0.f;
#pragma unroll
    for (int i = 0; i < 2; ++i) {
        const int off = i * 256 + lane * 4;
        const float4 hv = *reinterpret_cast<const float4*>(hrow + off);
        const float4 w0 = *reinterpret_cast<const float4*>(Gw + off);
        const float4 w1 = *reinterpret_cast<const float4*>(Gw + NN + off);
        const float t0 = tanhf(hv.x), t1 = tanhf(hv.y), t2 = tanhf(hv.z), t3 = tanhf(hv.w);
        g0 = fmaf(t0, w0.x, fmaf(t1, w0.y, fmaf(t2, w0.z, fmaf(t3, w0.w, g0))));
        g1 = fmaf(t0, w1.x, fmaf(t1, w1.y, fmaf(t2, w1.z, fmaf(t3, w1.w, g1))));
    }
#pragma unroll
    for (int off = 32; off > 0; off >>= 1) {
        g0 += __shfl_down(g0, off);
        g1 += __shfl_down(g1, off);
    }
    if (lane == 0) {
        g0 += Gb[0];
        g1 += Gb[1];
        geo[(size_t)wave * 2 + 0] = g0;
        geo[(size_t)wave * 2 + 1] = g1;
        const float dc[6] = {1.0f, 0.5f, -0.5f, -1.0f, -0.5f, 0.5f};
        const float ds[6] = {0.0f, 0.86602540378443865f, 0.86602540378443871f,
                             1.2246467991473532e-16f, -0.86602540378443837f,
                             -0.86602540378443860f};
#pragma unroll
        for (int k = 0; k < 6; ++k)
            rdo[(size_t)wave * 6 + k] = fmaf(g0, dc[k], g1 * ds[k]);
    }
}

extern "C" void kernel_launch(void* const* d_in, const int* in_sizes, int n_in,
                              void* d_out, int out_size, void* d_ws, size_t ws_size,
                              hipStream_t stream) {
    const float* h0 = (const float*)d_in[0];   // [512]
    const float* X  = (const float*)d_in[1];   // [64,1000,512]
    const float* W  = (const float*)d_in[2];   // [512,512]
    const float* Gw = (const float*)d_in[3];   // [2,512]
    const float* Gb = (const float*)d_in[4];   // [2]

    float* out = (float*)d_out;
    float* hid = out;                                   // [T*B*N]
    float* geo = out + (size_t)TT * BB * NN;            // [T*B*2]
    float* rdo = geo + (size_t)TT * BB * 2;             // [T*B*6]

    // Packed f16 W: 512 KB. Fall back to the geo+readout region (2 MB,
    // written only by the later geo_read pass) if ws is too small.
    const size_t wp_bytes = (size_t)NN * NN * sizeof(unsigned short);
    u32* Wp = (ws_size >= wp_bytes) ? (u32*)d_ws : (u32*)geo;

    pack_w<<<NN, 256, 0, stream>>>(W, Wp);
    rnn_scan<<<BB, 1024, 0, stream>>>(h0, X, Wp, hid);
    geo_read<<<(TT * BB) / 4, 256, 0, stream>>>(hid, Gw, Gb, geo, rdo);
}

// Round 3
// 1467.014 us; speedup vs baseline: 12.0546x; 5.2436x over previous
//
#include <hip/hip_runtime.h>

#define NN 512
#define BB 64
#define TT 1000

typedef unsigned int u32;
typedef _Float16 h2_t __attribute__((ext_vector_type(2)));

// acc += s[0]*w[0] + s[1]*w[1]  (f16 inputs, f32 accumulate) — v_dot2_f32_f16
__device__ inline float fdot2(u32 su, u32 wu, float acc) {
#if __has_builtin(__builtin_amdgcn_fdot2)
    return __builtin_amdgcn_fdot2(__builtin_bit_cast(h2_t, su),
                                  __builtin_bit_cast(h2_t, wu), acc, false);
#else
    h2_t s = __builtin_bit_cast(h2_t, su);
    h2_t w = __builtin_bit_cast(h2_t, wu);
    return fmaf((float)s[0], (float)w[0], fmaf((float)s[1], (float)w[1], acc));
#endif
}

// ---------------------------------------------------------------------------
// Pack W[n][k] (f32) -> Wp[kp][n] (u32 = half2(W[n][2kp], W[n][2kp+1])).
// ---------------------------------------------------------------------------
__global__ __launch_bounds__(256) void pack_w(const float* __restrict__ W,
                                              u32* __restrict__ Wp) {
    const int n = blockIdx.x;      // 0..511
    const int j = threadIdx.x;     // kp 0..255
    const float2 w = reinterpret_cast<const float2*>(W + (size_t)n * NN)[j];
    h2_t h;
    h[0] = (_Float16)w.x;
    h[1] = (_Float16)w.y;
    Wp[(size_t)j * NN + n] = __builtin_bit_cast(u32, h);
}

// ---------------------------------------------------------------------------
// Persistent scan, W fully CU-resident: one WG per batch, 512 threads
// (8 waves, 2/SIMD, VGPR cap 256). Thread (ks=tid>>7, c=tid&127) owns
// k in [ks*128, ks*128+128) x columns {4c..4c+3}:
//   - kp-local 0..47  (48 uint4 = 192 VGPRs)          -> registers, loaded once
//   - kp-local 48..63 (16 uint4 = 64 dwords = 128 KB) -> LDS, loaded once
// Per step: tanh->LDS(f16) | bar | 256 dot2 (s via same-address LDS broadcast,
// W from VGPR/LDS) | part write | bar | 4-way k-reduce + update + store.
// Zero W memory traffic inside the T-loop.
// ---------------------------------------------------------------------------
__global__ __launch_bounds__(512, 2) void rnn_scan(const float* __restrict__ h0v,
                                                   const float* __restrict__ X,
                                                   const u32* __restrict__ Wp,
                                                   float* __restrict__ hid) {
    const int b = blockIdx.x;
    const int tid = threadIdx.x;     // tid == owned hidden index n
    const int c = tid & 127;
    const int ks = tid >> 7;

    __shared__ __attribute__((aligned(16))) unsigned short th_h[NN];   // 1 KB
    __shared__ uint4 wlds[4 * 16 * 128];                                // 128 KB
    __shared__ float4 part4[4][128];                                    // 8 KB

    // ---- prologue: stage W into VGPRs + LDS (once) ----
    const uint4* wp4 = reinterpret_cast<const uint4*>(Wp);  // rows of 128 uint4
    uint4 wv[48];
#pragma unroll
    for (int j = 0; j < 48; ++j)
        wv[j] = wp4[(size_t)(ks * 64 + j) * 128 + c];
#pragma unroll
    for (int j = 0; j < 16; ++j)
        wlds[(ks * 16 + j) * 128 + c] = wp4[(size_t)(ks * 64 + 48 + j) * 128 + c];

    const float* xb = X + (size_t)b * TT * NN;
    float h = h0v[tid];
    float xn = xb[tid];
    __syncthreads();

    const uint4* thv = reinterpret_cast<const uint4*>(th_h);
    const float* pf = reinterpret_cast<const float*>(part4);  // pf[ks*512 + n]
    const uint4* wl = &wlds[ks * 16 * 128 + c];                // + j*128

    for (int t = 0; t < TT; ++t) {
        {
            const _Float16 hh = (_Float16)tanhf(h);
            th_h[tid] = __builtin_bit_cast(unsigned short, hh);
        }
        __syncthreads();

        // Prefetch next x (HBM/L3 latency hides under the matvec).
        float xnext = (t + 1 < TT) ? xb[(size_t)(t + 1) * NN + tid] : 0.f;

        float a0 = 0.f, a1 = 0.f, a2 = 0.f, a3 = 0.f;
        // --- VGPR-resident W: kp-local 0..47 (q = group of 4 kp = 8 k) ---
#pragma unroll
        for (int q = 0; q < 12; ++q) {
            const uint4 s = thv[ks * 16 + q];   // same addr across wave: broadcast
            const uint4 w0 = wv[4 * q + 0];
            const uint4 w1 = wv[4 * q + 1];
            const uint4 w2 = wv[4 * q + 2];
            const uint4 w3 = wv[4 * q + 3];
            a0 = fdot2(s.x, w0.x, a0); a1 = fdot2(s.x, w0.y, a1);
            a2 = fdot2(s.x, w0.z, a2); a3 = fdot2(s.x, w0.w, a3);
            a0 = fdot2(s.y, w1.x, a0); a1 = fdot2(s.y, w1.y, a1);
            a2 = fdot2(s.y, w1.z, a2); a3 = fdot2(s.y, w1.w, a3);
            a0 = fdot2(s.z, w2.x, a0); a1 = fdot2(s.z, w2.y, a1);
            a2 = fdot2(s.z, w2.z, a2); a3 = fdot2(s.z, w2.w, a3);
            a0 = fdot2(s.w, w3.x, a0); a1 = fdot2(s.w, w3.y, a1);
            a2 = fdot2(s.w, w3.z, a2); a3 = fdot2(s.w, w3.w, a3);
        }
        // --- LDS-resident W: kp-local 48..63 ---
#pragma unroll
        for (int q = 0; q < 4; ++q) {
            const uint4 s = thv[ks * 16 + 12 + q];
            const uint4 w0 = wl[(4 * q + 0) * 128];
            const uint4 w1 = wl[(4 * q + 1) * 128];
            const uint4 w2 = wl[(4 * q + 2) * 128];
            const uint4 w3 = wl[(4 * q + 3) * 128];
            a0 = fdot2(s.x, w0.x, a0); a1 = fdot2(s.x, w0.y, a1);
            a2 = fdot2(s.x, w0.z, a2); a3 = fdot2(s.x, w0.w, a3);
            a0 = fdot2(s.y, w1.x, a0); a1 = fdot2(s.y, w1.y, a1);
            a2 = fdot2(s.y, w1.z, a2); a3 = fdot2(s.y, w1.w, a3);
            a0 = fdot2(s.z, w2.x, a0); a1 = fdot2(s.z, w2.y, a1);
            a2 = fdot2(s.z, w2.z, a2); a3 = fdot2(s.z, w2.w, a3);
            a0 = fdot2(s.w, w3.x, a0); a1 = fdot2(s.w, w3.y, a1);
            a2 = fdot2(s.w, w3.z, a2); a3 = fdot2(s.w, w3.w, a3);
        }
        part4[ks][c] = make_float4(a0, a1, a2, a3);
        __syncthreads();

        // k-reduce for n = tid: pf[ks*512 + n], ks = 0..3
        const float s = (pf[tid] + pf[512 + tid]) + (pf[1024 + tid] + pf[1536 + tid]);
        h = 0.9f * h + 0.1f * (s + xn);
        hid[((size_t)t * BB + b) * NN + tid] = h;
        xn = xnext;
        // No third barrier: next phase writes th_h (guarded by bar1 before the
        // reads), and part4 is rewritten only after bar1.
    }
}

// ---------------------------------------------------------------------------
// geometry = tanh(hidden_t) @ G_w.T + G_b ; readout = geometry @ D.T
// ---------------------------------------------------------------------------
__global__ __launch_bounds__(256) void geo_read(const float* __restrict__ hid,
                                                const float* __restrict__ Gw,
                                                const float* __restrict__ Gb,
                                                float* __restrict__ geo,
                                                float* __restrict__ rdo) {
    const int wave = (int)((blockIdx.x * 256 + threadIdx.x) >> 6);  // 0..63999
    const int lane = threadIdx.x & 63;
    if (wave >= TT * BB) return;

    const float* hrow = hid + (size_t)wave * NN;
    float g0 = 0.f, g1 = 0.f;
#pragma unroll
    for (int i = 0; i < 2; ++i) {
        const int off = i * 256 + lane * 4;
        const float4 hv = *reinterpret_cast<const float4*>(hrow + off);
        const float4 w0 = *reinterpret_cast<const float4*>(Gw + off);
        const float4 w1 = *reinterpret_cast<const float4*>(Gw + NN + off);
        const float t0 = tanhf(hv.x), t1 = tanhf(hv.y), t2 = tanhf(hv.z), t3 = tanhf(hv.w);
        g0 = fmaf(t0, w0.x, fmaf(t1, w0.y, fmaf(t2, w0.z, fmaf(t3, w0.w, g0))));
        g1 = fmaf(t0, w1.x, fmaf(t1, w1.y, fmaf(t2, w1.z, fmaf(t3, w1.w, g1))));
    }
#pragma unroll
    for (int off = 32; off > 0; off >>= 1) {
        g0 += __shfl_down(g0, off);
        g1 += __shfl_down(g1, off);
    }
    if (lane == 0) {
        g0 += Gb[0];
        g1 += Gb[1];
        geo[(size_t)wave * 2 + 0] = g0;
        geo[(size_t)wave * 2 + 1] = g1;
        const float dc[6] = {1.0f, 0.5f, -0.5f, -1.0f, -0.5f, 0.5f};
        const float ds[6] = {0.0f, 0.86602540378443865f, 0.86602540378443871f,
                             1.2246467991473532e-16f, -0.86602540378443837f,
                             -0.86602540378443860f};
#pragma unroll
        for (int k = 0; k < 6; ++k)
            rdo[(size_t)wave * 6 + k] = fmaf(g0, dc[k], g1 * ds[k]);
    }
}

extern "C" void kernel_launch(void* const* d_in, const int* in_sizes, int n_in,
                              void* d_out, int out_size, void* d_ws, size_t ws_size,
                              hipStream_t stream) {
    const float* h0 = (const float*)d_in[0];   // [512]
    const float* X  = (const float*)d_in[1];   // [64,1000,512]
    const float* W  = (const float*)d_in[2];   // [512,512]
    const float* Gw = (const float*)d_in[3];   // [2,512]
    const float* Gb = (const float*)d_in[4];   // [2]

    float* out = (float*)d_out;
    float* hid = out;                                   // [T*B*N]
    float* geo = out + (size_t)TT * BB * NN;            // [T*B*2]
    float* rdo = geo + (size_t)TT * BB * 2;             // [T*B*6]

    // Packed f16 W: 512 KB. Fallback: geo+rdo region (2 MB, overwritten later).
    const size_t wp_bytes = (size_t)NN * NN * sizeof(unsigned short);
    u32* Wp = (ws_size >= wp_bytes) ? (u32*)d_ws : (u32*)geo;

    pack_w<<<NN, 256, 0, stream>>>(W, Wp);
    rnn_scan<<<BB, 512, 0, stream>>>(h0, X, Wp, hid);
    geo_read<<<(TT * BB) / 4, 256, 0, stream>>>(hid, Gw, Gb, geo, rdo);
}